// Round 1
// baseline (9715.540 us; speedup 1.0000x reference)
//
#include <hip/hip_runtime.h>
#include <hip/hip_bf16.h>
#include <math.h>

// ---------------------------------------------------------------------------
// Bidirectional LSTM encoder (final states only) -> 2-layer AR decoder (64
// steps) -> vocab-3 projection.
// Structure:
//   init_k      : zero h buffers / flags (must run every call: ws not re-poisoned)
//   convert_k   : x, ew_ih_{f,b} -> bf16; bias sums
//   xproj_gemm  : bf16 MFMA GEMM, Xproj[dir][t][b][1024] fp32 (+bias), dir1 time-reversed
//   encoder_k   : persistent, 256 blocks (1/CU), fp32, flag-synced over 512 steps
//   decoder_k   : persistent, 256 blocks, fp32, 2 layers flag-pipelined, 64 steps
//   logits_k    : h1 history @ lw^T + lb
// ---------------------------------------------------------------------------

typedef unsigned short u16;
typedef __bf16 bf16x8v __attribute__((ext_vector_type(8)));
typedef u16 u16x8 __attribute__((ext_vector_type(8)));
typedef float f32x4 __attribute__((ext_vector_type(4)));

__device__ __forceinline__ u16 f2bf(float f) {
  unsigned u = __builtin_bit_cast(unsigned, f);
  u += 0x7fffu + ((u >> 16) & 1u);   // round-to-nearest-even
  return (u16)(u >> 16);
}

__device__ __forceinline__ void spin_ge(int* f, int v) {
  while (__hip_atomic_load(f, __ATOMIC_ACQUIRE, __HIP_MEMORY_SCOPE_AGENT) < v) {
    __builtin_amdgcn_s_sleep(1);
  }
}

// ---------------------------------------------------------------------------
__global__ __launch_bounds__(256) void init_k(float* hbuf, float* inpb, int* ef, int* df) {
  int gid = blockIdx.x * 256 + threadIdx.x;   // grid 512*256 = 131072
  hbuf[gid] = 0.f;                            // [2 par][2 dir][128][256]
  if (gid < 65536) inpb[gid] = 0.f;           // decoder inp buffer (both parities)
  if (gid < 256) { ef[gid] = 0; df[gid] = 0; }
}

// ---------------------------------------------------------------------------
__global__ __launch_bounds__(256) void convert_k(
    const float* __restrict__ x,
    const float* __restrict__ wfm, const float* __restrict__ wbm,
    const float* __restrict__ bif, const float* __restrict__ bhf,
    const float* __restrict__ bib, const float* __restrict__ bhb,
    const float* __restrict__ dbi0, const float* __restrict__ dbh0,
    const float* __restrict__ dbi1, const float* __restrict__ dbh1,
    u16* __restrict__ xbf, u16* __restrict__ wbf,
    float* __restrict__ bias2, float* __restrict__ dbias) {
  const long NX = 67108864L, NW = 1048576L;
  long gid = (long)blockIdx.x * 256 + threadIdx.x;
  if (gid < 1024) {
    bias2[gid]        = bif[gid] + bhf[gid];
    bias2[1024 + gid] = bib[gid] + bhb[gid];
    dbias[gid]        = dbi0[gid] + dbh0[gid];
    dbias[1024 + gid] = dbi1[gid] + dbh1[gid];
  }
  long total4 = (NX + 2 * NW) >> 2;
  long stride = (long)gridDim.x * 256;
  for (long q = gid; q < total4; q += stride) {
    long i = q << 2;
    const float* src; u16* dst; long o;
    if (i < NX)            { src = x;   dst = xbf;      o = i; }
    else if (i < NX + NW)  { src = wfm; dst = wbf;      o = i - NX; }
    else                   { src = wbm; dst = wbf + NW; o = i - NX - NW; }
    float4 v = *(const float4*)&src[o];
    dst[o + 0] = f2bf(v.x); dst[o + 1] = f2bf(v.y);
    dst[o + 2] = f2bf(v.z); dst[o + 3] = f2bf(v.w);
  }
}

// ---------------------------------------------------------------------------
// Xproj GEMM: per dir, C[m][n] = sum_k Xbf[m][k] * Wbf[n][k] + bias[n]
// 128x128 tile, 4 waves each 64x64 (4x4 frags of 16x16x32 bf16 MFMA).
// dir=1 reads time-reversed x rows (tile = one t since BM == B == 128).
__global__ __launch_bounds__(256) void xproj_gemm(
    const u16* __restrict__ xbf, const u16* __restrict__ wbf,
    const float* __restrict__ bias2, float* __restrict__ xp) {
  __shared__ u16 Al[128][40];   // +8 pad: 2-way bank alias only (free)
  __shared__ u16 Bl[128][40];
  int bid = blockIdx.x;
  int dir = bid >> 12, rem = bid & 4095, tb = rem >> 3, nb = rem & 7;
  int tsrc = dir ? (511 - tb) : tb;
  const u16* A  = xbf + (long)tsrc * (128 * 1024);
  const u16* Bw = wbf + (long)dir * (1024 * 1024) + (long)nb * (128 * 1024);
  float* C = xp + ((long)(dir * 512 + tb) * 128) * 1024 + nb * 128;
  const float* bias = bias2 + dir * 1024 + nb * 128;

  int tid = threadIdx.x, lane = tid & 63, wid = tid >> 6;
  int wr = wid >> 1, wc = wid & 1;
  int srow = tid >> 1, scol = (tid & 1) * 16;
  int fr = lane & 15, ko = lane >> 4;

  f32x4 acc[4][4] = {};
  for (int k0 = 0; k0 < 1024; k0 += 32) {
    u16x8 a0 = *(const u16x8*)&A[(long)srow * 1024 + k0 + scol];
    u16x8 a1 = *(const u16x8*)&A[(long)srow * 1024 + k0 + scol + 8];
    u16x8 b0 = *(const u16x8*)&Bw[(long)srow * 1024 + k0 + scol];
    u16x8 b1 = *(const u16x8*)&Bw[(long)srow * 1024 + k0 + scol + 8];
    __syncthreads();
    *(u16x8*)&Al[srow][scol]     = a0;
    *(u16x8*)&Al[srow][scol + 8] = a1;
    *(u16x8*)&Bl[srow][scol]     = b0;
    *(u16x8*)&Bl[srow][scol + 8] = b1;
    __syncthreads();
    bf16x8v af[4], bf[4];
#pragma unroll
    for (int i = 0; i < 4; ++i)
      af[i] = __builtin_bit_cast(bf16x8v, *(const u16x8*)&Al[wr * 64 + i * 16 + fr][ko * 8]);
#pragma unroll
    for (int jf = 0; jf < 4; ++jf)
      bf[jf] = __builtin_bit_cast(bf16x8v, *(const u16x8*)&Bl[wc * 64 + jf * 16 + fr][ko * 8]);
#pragma unroll
    for (int i = 0; i < 4; ++i)
#pragma unroll
      for (int jf = 0; jf < 4; ++jf)
        acc[i][jf] = __builtin_amdgcn_mfma_f32_16x16x32_bf16(af[i], bf[jf], acc[i][jf], 0, 0, 0);
  }
  int fq = lane >> 4;
#pragma unroll
  for (int i = 0; i < 4; ++i)
#pragma unroll
    for (int jf = 0; jf < 4; ++jf) {
      int col = wc * 64 + jf * 16 + fr;
      float bv = bias[col];
#pragma unroll
      for (int e = 0; e < 4; ++e) {
        int row = wr * 64 + i * 16 + fq * 4 + e;
        C[(long)row * 1024 + col] = acc[i][jf][e] + bv;
      }
    }
}

// ---------------------------------------------------------------------------
// Persistent encoder: 256 blocks = dir(2) x bgroup(16; 8 rows) x jgroup(8; 32 cols).
// Thread (j=tid&31, ks=tid>>5): k-slice of 32; w_hh slice in 128 VGPRs (static idx).
// h_t in hbuf[t&1][dir][128][256]; flag[d][bg][jg] = completed steps (agent scope).
__global__ __launch_bounds__(256) void encoder_k(
    const float* __restrict__ whf, const float* __restrict__ whb,
    const float* __restrict__ xp, float* hbuf, int* eflags,
    float* h0b, float* h1b, float* cfb, float* cbb) {
  int bid = blockIdx.x;
  int d = bid >> 7, bg = (bid >> 3) & 15, jg = bid & 7;
  int tid = threadIdx.x;
  int j = tid & 31, ks = tid >> 5;
  const float* whh = d ? whb : whf;   // [1024][256]

  float w[4][32];
#pragma unroll
  for (int g = 0; g < 4; ++g) {
    const float* wp = whh + (long)(g * 256 + jg * 32 + j) * 256 + ks * 32;
#pragma unroll
    for (int q = 0; q < 8; ++q) {
      float4 v = *(const float4*)&wp[q * 4];
      w[g][q * 4 + 0] = v.x; w[g][q * 4 + 1] = v.y;
      w[g][q * 4 + 2] = v.z; w[g][q * 4 + 3] = v.w;
    }
  }

  __shared__ float hl[2048];    // h_t [8 rows][256]
  __shared__ float red[8192];   // partials [ks 8][r 8][g 4][j 32]
  int r_e = tid >> 5, j_e = tid & 31;
  float c_r = 0.f;
  int fbase = (d * 16 + bg) * 8;

  for (int t = 0; t < 512; ++t) {
    float xpv[4];
#pragma unroll
    for (int g = 0; g < 4; ++g)   // prefetch before spin; independent of h
      xpv[g] = xp[((long)(d * 512 + t) * 128 + bg * 8 + r_e) * 1024 + g * 256 + jg * 32 + j_e];

    if (tid < 8) spin_ge(&eflags[fbase + tid], t);
    __syncthreads();

    const float* hsrc = hbuf + (((t & 1) * 2 + d) * 128 + bg * 8) * 256;
    *(float4*)&hl[tid * 8]     = *(const float4*)&hsrc[tid * 8];
    *(float4*)&hl[tid * 8 + 4] = *(const float4*)&hsrc[tid * 8 + 4];
    __syncthreads();

    float acc[8][4] = {};
#pragma unroll
    for (int r = 0; r < 8; ++r)
#pragma unroll
      for (int q = 0; q < 8; ++q) {
        float4 hv = *(const float4*)&hl[r * 256 + ks * 32 + q * 4];
#pragma unroll
        for (int g = 0; g < 4; ++g)
          acc[r][g] += hv.x * w[g][q * 4 + 0] + hv.y * w[g][q * 4 + 1]
                     + hv.z * w[g][q * 4 + 2] + hv.w * w[g][q * 4 + 3];
      }
#pragma unroll
    for (int r = 0; r < 8; ++r)
#pragma unroll
      for (int g = 0; g < 4; ++g)
        red[((ks * 8 + r) * 4 + g) * 32 + j] = acc[r][g];
    __syncthreads();

    {
      float gv[4];
#pragma unroll
      for (int g = 0; g < 4; ++g) {
        float s = xpv[g];
#pragma unroll
        for (int p = 0; p < 8; ++p) s += red[((p * 8 + r_e) * 4 + g) * 32 + j_e];
        gv[g] = s;
      }
      float iv = 1.f / (1.f + expf(-gv[0]));
      float fv = 1.f / (1.f + expf(-gv[1]));
      float gg = tanhf(gv[2]);
      float ov = 1.f / (1.f + expf(-gv[3]));
      c_r = fv * c_r + iv * gg;
      float hval = ov * tanhf(c_r);
      int rowg = bg * 8 + r_e, colg = jg * 32 + j_e;
      hbuf[((((t + 1) & 1) * 2 + d) * 128 + rowg) * 256 + colg] = hval;
      if (t == 511) {   // final states -> decoder init (parity-1 slot = h_{-1})
        (d ? h1b : h0b)[32768 + rowg * 256 + colg] = hval;
        (d ? cbb : cfb)[rowg * 256 + colg] = c_r;
      }
    }
    __syncthreads();   // drain all h stores before posting
    if (tid == 0)
      __hip_atomic_store(&eflags[fbase + jg], t + 1, __ATOMIC_RELEASE, __HIP_MEMORY_SCOPE_AGENT);
  }
}

// ---------------------------------------------------------------------------
// Persistent decoder: 256 blocks = L(2) x bg(16) x jg(8); 512 threads; K=512.
// L0: gates = [inp | h0_prev] @ [dw_ih0|dw_hh0]^T ; L1: [h0_new | h1_prev].
// flags[L][bg][jg] = completed steps.
__global__ __launch_bounds__(512) void decoder_k(
    const float* __restrict__ wih0, const float* __restrict__ whh0,
    const float* __restrict__ wih1, const float* __restrict__ whh1,
    const float* __restrict__ dbias,
    float* h0b, float* h1b, float* inpb,
    const float* __restrict__ cfb, const float* __restrict__ cbb,
    float* hist, int* dflags) {
  int bid = blockIdx.x;
  int L = bid >> 7, bg = (bid >> 3) & 15, jg = bid & 7;
  int tid = threadIdx.x;
  int j = tid & 31, ks = tid >> 5;   // ks 0..15 over K=512
  const float* wih = L ? wih1 : wih0;
  const float* whh = L ? whh1 : whh0;

  float w[4][32];
#pragma unroll
  for (int g = 0; g < 4; ++g) {
    int grow = g * 256 + jg * 32 + j;
#pragma unroll
    for (int q = 0; q < 8; ++q) {
      int k = ks * 32 + q * 4;
      const float* src = (k < 256) ? &wih[(long)grow * 256 + k]
                                   : &whh[(long)grow * 256 + k - 256];
      float4 v = *(const float4*)src;
      w[g][q * 4 + 0] = v.x; w[g][q * 4 + 1] = v.y;
      w[g][q * 4 + 2] = v.z; w[g][q * 4 + 3] = v.w;
    }
  }

  __shared__ float xl[4096];     // [8 rows][512] = [x(256) | h(256)]
  __shared__ float red[16384];   // [ks 16][r 8][g 4][j 32]
  float c_r = 0.f;
  if (tid < 256)
    c_r = (L ? cbb : cfb)[(bg * 8 + (tid >> 5)) * 256 + jg * 32 + (tid & 31)];
  int srow = tid >> 6, scol = (tid & 63) * 8;

  for (int t = 0; t < 64; ++t) {
    if (tid < 16) {
      int p = tid & 7, which = tid >> 3;
      int need = (which == 0) ? ((L == 0) ? t : t + 1) : t;
      spin_ge(&dflags[which * 128 + bg * 8 + p], need);
    }
    __syncthreads();

    const float* xsrc  = (L == 0) ? inpb + (t & 1) * 32768 : h0b + (t & 1) * 32768;
    const float* hsrc2 = (L == 0) ? h0b + (((t + 1) & 1)) * 32768 : h1b + (((t + 1) & 1)) * 32768;
    {
      const float* s = (scol < 256) ? &xsrc[(bg * 8 + srow) * 256 + scol]
                                    : &hsrc2[(bg * 8 + srow) * 256 + scol - 256];
      *(float4*)&xl[srow * 512 + scol]     = *(const float4*)&s[0];
      *(float4*)&xl[srow * 512 + scol + 4] = *(const float4*)&s[4];
    }
    __syncthreads();

    float acc[8][4] = {};
#pragma unroll
    for (int r = 0; r < 8; ++r)
#pragma unroll
      for (int q = 0; q < 8; ++q) {
        float4 hv = *(const float4*)&xl[r * 512 + ks * 32 + q * 4];
#pragma unroll
        for (int g = 0; g < 4; ++g)
          acc[r][g] += hv.x * w[g][q * 4 + 0] + hv.y * w[g][q * 4 + 1]
                     + hv.z * w[g][q * 4 + 2] + hv.w * w[g][q * 4 + 3];
      }
#pragma unroll
    for (int r = 0; r < 8; ++r)
#pragma unroll
      for (int g = 0; g < 4; ++g)
        red[((ks * 8 + r) * 4 + g) * 32 + j] = acc[r][g];
    __syncthreads();

    if (tid < 256) {
      int r_e = tid >> 5, j_e = tid & 31;
      float gv[4];
#pragma unroll
      for (int g = 0; g < 4; ++g) {
        float s = dbias[L * 1024 + g * 256 + jg * 32 + j_e];
#pragma unroll
        for (int p = 0; p < 16; ++p) s += red[((p * 8 + r_e) * 4 + g) * 32 + j_e];
        gv[g] = s;
      }
      float iv = 1.f / (1.f + expf(-gv[0]));
      float fv = 1.f / (1.f + expf(-gv[1]));
      float gg = tanhf(gv[2]);
      float ov = 1.f / (1.f + expf(-gv[3]));
      c_r = fv * c_r + iv * gg;
      float hval = ov * tanhf(c_r);
      int rowg = bg * 8 + r_e, colg = jg * 32 + j_e;
      if (L == 0) {
        h0b[(t & 1) * 32768 + rowg * 256 + colg] = hval;
      } else {
        h1b[(t & 1) * 32768 + rowg * 256 + colg] = hval;
        inpb[((t + 1) & 1) * 32768 + rowg * 256 + colg] = hval;   // feedback
        hist[((long)t * 128 + rowg) * 256 + colg] = hval;
      }
    }
    __syncthreads();
    if (tid == 0)
      __hip_atomic_store(&dflags[L * 128 + bg * 8 + jg], t + 1, __ATOMIC_RELEASE, __HIP_MEMORY_SCOPE_AGENT);
  }
}

// ---------------------------------------------------------------------------
__global__ __launch_bounds__(256) void logits_k(
    const float* __restrict__ hist, const float* __restrict__ lw,
    const float* __restrict__ lb, float* __restrict__ out) {
  int widx = threadIdx.x >> 6, lane = threadIdx.x & 63;
  int row = blockIdx.x * 4 + widx;   // 0..8191 = t*128+b
  const float* h = hist + (long)row * 256;
  float4 hv = *(const float4*)&h[lane * 4];
  float s[3];
#pragma unroll
  for (int v = 0; v < 3; ++v) {
    float4 wv = *(const float4*)&lw[v * 256 + lane * 4];
    float p = hv.x * wv.x + hv.y * wv.y + hv.z * wv.z + hv.w * wv.w;
#pragma unroll
    for (int o = 32; o > 0; o >>= 1) p += __shfl_xor(p, o, 64);
    s[v] = p;
  }
  if (lane == 0) {
    out[row * 3 + 0] = s[0] + lb[0];
    out[row * 3 + 1] = s[1] + lb[1];
    out[row * 3 + 2] = s[2] + lb[2];
  }
}

// ---------------------------------------------------------------------------
extern "C" void kernel_launch(void* const* d_in, const int* in_sizes, int n_in,
                              void* d_out, int out_size, void* d_ws, size_t ws_size,
                              hipStream_t stream) {
  const float* x     = (const float*)d_in[0];
  const float* ewihf = (const float*)d_in[1];
  const float* ewhhf = (const float*)d_in[2];
  const float* ebihf = (const float*)d_in[3];
  const float* ebhhf = (const float*)d_in[4];
  const float* ewihb = (const float*)d_in[5];
  const float* ewhhb = (const float*)d_in[6];
  const float* ebihb = (const float*)d_in[7];
  const float* ebhhb = (const float*)d_in[8];
  const float* dwih0 = (const float*)d_in[9];
  const float* dwhh0 = (const float*)d_in[10];
  const float* dbih0 = (const float*)d_in[11];
  const float* dbhh0 = (const float*)d_in[12];
  const float* dwih1 = (const float*)d_in[13];
  const float* dwhh1 = (const float*)d_in[14];
  const float* dbih1 = (const float*)d_in[15];
  const float* dbhh1 = (const float*)d_in[16];
  const float* lw    = (const float*)d_in[17];
  const float* lb    = (const float*)d_in[18];
  float* out = (float*)d_out;
  (void)in_sizes; (void)n_in; (void)out_size; (void)ws_size;

  char* wsb = (char*)d_ws;
  size_t off = 0;
  auto take = [&](size_t bytes) -> char* {
    char* p = wsb + off;
    off = (off + bytes + 255) & ~(size_t)255;
    return p;
  };
  u16*   xbf   = (u16*)take(67108864ull * 2);    // x as bf16 [512*128][1024]
  u16*   wbf   = (u16*)take(2097152ull * 2);     // ew_ih f,b as bf16
  float* xp    = (float*)take(134217728ull * 4); // Xproj [2][512][128][1024]
  float* bias2 = (float*)take(2048 * 4);
  float* dbias = (float*)take(2048 * 4);
  float* hbuf  = (float*)take(131072 * 4);       // [2 par][2 dir][128][256]
  float* h0b   = (float*)take(65536 * 4);        // [2 par][128][256]
  float* h1b   = (float*)take(65536 * 4);
  float* inpb  = (float*)take(65536 * 4);
  float* cfb   = (float*)take(32768 * 4);
  float* cbb   = (float*)take(32768 * 4);
  float* hist  = (float*)take(2097152 * 4);      // h1 history [64][128][256]
  int*   ef    = (int*)take(256 * 4);
  int*   df    = (int*)take(256 * 4);

  init_k<<<512, 256, 0, stream>>>(hbuf, inpb, ef, df);
  convert_k<<<2048, 256, 0, stream>>>(x, ewihf, ewihb, ebihf, ebhhf, ebihb, ebhhb,
                                      dbih0, dbhh0, dbih1, dbhh1, xbf, wbf, bias2, dbias);
  xproj_gemm<<<8192, 256, 0, stream>>>(xbf, wbf, bias2, xp);
  encoder_k<<<256, 256, 0, stream>>>(ewhhf, ewhhb, xp, hbuf, ef, h0b, h1b, cfb, cbb);
  decoder_k<<<256, 512, 0, stream>>>(dwih0, dwhh0, dwih1, dwhh1, dbias,
                                     h0b, h1b, inpb, cfb, cbb, hist, df);
  logits_k<<<2048, 256, 0, stream>>>(hist, lw, lb, out);
}